// Round 1
// baseline (27.526 us; speedup 1.0000x reference)
//
#include <hip/hip_runtime.h>

#define LENGTH   256
#define VOLUME   (LENGTH * LENGTH)
#define N_STATES 256
#define ACTION_SHIFT_F 131072.0f   // 2 * BETA * VOLUME, BETA = 1
#define BPS      8                 // blocks per state
#define EPB      (VOLUME / BPS)    // 8192 elements per block
#define THREADS  256

__global__ __launch_bounds__(THREADS)
void action_partial(const float* __restrict__ state, float* __restrict__ ws)
{
    const int blk = blockIdx.x;
    const int n   = blk >> 3;      // state index
    const int b   = blk & 7;       // chunk within state
    const float* __restrict__ theta = state + (size_t)n * (2 * VOLUME);
    const float* __restrict__ phi   = theta + VOLUME;
    const int base = b * EPB;

    float acc = 0.0f;
    for (int it = 0; it < EPB / (4 * THREADS); ++it) {
        const int i = base + ((it * THREADS) + (int)threadIdx.x) * 4;

        const float4 tc = *reinterpret_cast<const float4*>(theta + i);
        const float4 pc = *reinterpret_cast<const float4*>(phi   + i);

        // up-neighbor row (roll +1 on axis 0): contiguous, aligned
        const int up = (i >= LENGTH) ? (i - LENGTH) : (i + (VOLUME - LENGTH));
        const float4 tu = *reinterpret_cast<const float4*>(theta + up);
        const float4 pu = *reinterpret_cast<const float4*>(phi   + up);

        // left-neighbor of element 0 of the group (may wrap within the row)
        const int c0 = i & (LENGTH - 1);
        const int l0 = (c0 == 0) ? (i + (LENGTH - 1)) : (i - 1);
        const float tl = theta[l0];
        const float pl = phi[l0];

        float tcv[4] = {tc.x, tc.y, tc.z, tc.w};
        float pcv[4] = {pc.x, pc.y, pc.z, pc.w};
        float tuv[4] = {tu.x, tu.y, tu.z, tu.w};
        float puv[4] = {pu.x, pu.y, pu.z, pu.w};

        float sc[4], cc[4], su[4], cu[4];
        #pragma unroll
        for (int j = 0; j < 4; ++j) {
            __sincosf(tcv[j], &sc[j], &cc[j]);
            __sincosf(tuv[j], &su[j], &cu[j]);
        }
        float sl, cl;
        __sincosf(tl, &sl, &cl);

        // vertical (up) interactions
        #pragma unroll
        for (int j = 0; j < 4; ++j)
            acc += cu[j] * cc[j] + su[j] * sc[j] * __cosf(puv[j] - pcv[j]);

        // horizontal (left) interactions; reuse center sincos as neighbor
        acc += cl * cc[0] + sl * sc[0] * __cosf(pl - pcv[0]);
        #pragma unroll
        for (int j = 1; j < 4; ++j)
            acc += cc[j-1] * cc[j] + sc[j-1] * sc[j] * __cosf(pcv[j-1] - pcv[j]);
    }

    // wave (64-lane) butterfly reduce, then cross-wave via LDS
    #pragma unroll
    for (int off = 32; off >= 1; off >>= 1)
        acc += __shfl_down(acc, off, 64);

    __shared__ float red[THREADS / 64];
    const int wave = threadIdx.x >> 6;
    const int lane = threadIdx.x & 63;
    if (lane == 0) red[wave] = acc;
    __syncthreads();
    if (threadIdx.x == 0) {
        float s = 0.0f;
        #pragma unroll
        for (int w = 0; w < THREADS / 64; ++w) s += red[w];
        ws[blk] = s;
    }
}

__global__ __launch_bounds__(N_STATES)
void action_final(const float* __restrict__ ws, float* __restrict__ out)
{
    const int n = threadIdx.x;   // one thread per state
    float s = 0.0f;
    #pragma unroll
    for (int b = 0; b < BPS; ++b) s += ws[n * BPS + b];
    out[n] = ACTION_SHIFT_F - s;   // -BETA * sum + shift, BETA = 1
}

extern "C" void kernel_launch(void* const* d_in, const int* in_sizes, int n_in,
                              void* d_out, int out_size, void* d_ws, size_t ws_size,
                              hipStream_t stream)
{
    const float* state = (const float*)d_in[0];
    // d_in[1] (shift table) is the fixed torus-neighbor map; computed analytically.
    float* ws  = (float*)d_ws;
    float* out = (float*)d_out;

    action_partial<<<dim3(N_STATES * BPS), dim3(THREADS), 0, stream>>>(state, ws);
    action_final<<<dim3(1), dim3(N_STATES), 0, stream>>>(ws, out);
}